// Round 9
// baseline (3017.169 us; speedup 1.0000x reference)
//
#include <hip/hip_runtime.h>

typedef _Float16 half_t;
typedef _Float16 h2_t __attribute__((ext_vector_type(2)));
typedef _Float16 h4_t __attribute__((ext_vector_type(4)));
typedef _Float16 h8_t __attribute__((ext_vector_type(8)));
typedef float f32x4 __attribute__((ext_vector_type(4)));
typedef unsigned int uint32;

#define BQ 64
#define TT 2048
#define EE 256
#define HH 256
#define CHK 32  // steps per staged gate chunk

#if defined(__has_builtin)
#if __has_builtin(__builtin_amdgcn_rcpf)
#define FRCP(x) __builtin_amdgcn_rcpf(x)
#endif
#endif
#ifndef FRCP
#define FRCP(x) (1.0f / (x))
#endif

// barrier that drains LDS only: chunk global_load_lds traffic stays in flight
__device__ __forceinline__ void barrier_lgkm() {
  asm volatile("s_waitcnt lgkmcnt(0)\n\ts_barrier" ::: "memory");
}

__device__ __forceinline__ void wait_vm0() {
  asm volatile("s_waitcnt vmcnt(0)" ::: "memory");
}

// async global->LDS, 16B per lane; LDS dest is wave-uniform base (+lane*16 by HW),
// global src is per-lane (pass base, HW does NOT add lane offset -> add it here).
__device__ __forceinline__ void gl2lds16(const void* gsrc_lane, void* lds_base) {
  __builtin_amdgcn_global_load_lds(
      (const __attribute__((address_space(1))) void*)gsrc_lane,
      (__attribute__((address_space(3))) void*)lds_base, 16, 0, 0);
}

__device__ __forceinline__ float sigmoid_f(float x) {
  return FRCP(1.f + __expf(-x));
}

__device__ __forceinline__ h8_t cvt_w8(const float* p) {
  float4 a0 = *(const float4*)p;
  float4 a1 = *(const float4*)(p + 4);
  h8_t w;
  w[0] = (half_t)a0.x; w[1] = (half_t)a0.y; w[2] = (half_t)a0.z; w[3] = (half_t)a0.w;
  w[4] = (half_t)a1.x; w[5] = (half_t)a1.y; w[6] = (half_t)a1.z; w[7] = (half_t)a1.w;
  return w;
}

#define MFMA16(a, b, c) __builtin_amdgcn_mfma_f32_16x16x32_f16((a), (b), (c), 0, 0, 0)

// ---------------- Phase A: input projections ----------------
__device__ __forceinline__ const float4* wsrc(int n, int col, const float* Wu,
                                              const float* Wr, const float* Wn) {
  const int gsel = n >> 8, jj = n & 255;
  const float* W = (gsel == 0) ? Wu : (gsel == 1) ? Wr : Wn;
  return (const float4*)(W + (size_t)jj * (EE + HH) + col);
}

__global__ __launch_bounds__(256) void gru_xproj(
    const float* __restrict__ x,
    const float* __restrict__ Wu, const float* __restrict__ bu,
    const float* __restrict__ Wr, const float* __restrict__ br,
    const float* __restrict__ Wn, const float* __restrict__ bn,
    float* __restrict__ hs, half_t* __restrict__ nbuf, int t0)
{
  __shared__ half_t Asm[64][264];     // +8 pad: 2-way banks only
  __shared__ half_t Bsm[2][48][264];
  const int tid = threadIdx.x;
  const int tl = blockIdx.x;
  const int tcTotal = gridDim.x;      // steps in this launch (nbuf stride)
  const int t = t0 + tl;

#pragma unroll
  for (int k = 0; k < 16; ++k) {
    int q = tid + 256 * k;
    int row = q >> 6, col = (q & 63) * 4;
    float4 v = *(const float4*)(x + ((size_t)row * TT + t) * EE + col);
    h4_t h; h[0] = (half_t)v.x; h[1] = (half_t)v.y; h[2] = (half_t)v.z; h[3] = (half_t)v.w;
    *(h4_t*)(&Asm[row][col]) = h;
  }
#pragma unroll
  for (int k = 0; k < 12; ++k) {
    int q = tid + 256 * k;
    int row = q >> 6, col = (q & 63) * 4;
    float4 v = *wsrc(row, col, Wu, Wr, Wn);
    h4_t h; h[0] = (half_t)v.x; h[1] = (half_t)v.y; h[2] = (half_t)v.z; h[3] = (half_t)v.w;
    *(h4_t*)(&Bsm[0][row][col]) = h;
  }
  __syncthreads();

  const int wv = tid >> 6, lane = tid & 63;
  const int rowa = wv * 16 + (lane & 15);
  const int koff = (lane >> 4) * 8;
  h8_t af[8];
#pragma unroll
  for (int ki = 0; ki < 8; ++ki) af[ki] = *(const h8_t*)&Asm[rowa][ki * 32 + koff];

  const int colc = lane & 15;
  const int rbase = wv * 16 + (lane >> 4) * 4;

  for (int c = 0; c < 16; ++c) {
    const int cur = c & 1;
    float4 pf[12];
    if (c < 15) {
#pragma unroll
      for (int k = 0; k < 12; ++k) {
        int q = tid + 256 * k;
        int row = q >> 6, col = (q & 63) * 4;
        pf[k] = *wsrc((c + 1) * 48 + row, col, Wu, Wr, Wn);
      }
    }
    f32x4 acc0 = {0.f, 0.f, 0.f, 0.f}, acc1 = acc0, acc2 = acc0;
#pragma unroll
    for (int ki = 0; ki < 8; ++ki) {
      h8_t b0 = *(const h8_t*)&Bsm[cur][0  + (lane & 15)][ki * 32 + koff];
      h8_t b1 = *(const h8_t*)&Bsm[cur][16 + (lane & 15)][ki * 32 + koff];
      h8_t b2 = *(const h8_t*)&Bsm[cur][32 + (lane & 15)][ki * 32 + koff];
      acc0 = MFMA16(af[ki], b0, acc0);
      acc1 = MFMA16(af[ki], b1, acc1);
      acc2 = MFMA16(af[ki], b2, acc2);
    }
    if (c < 15) {
#pragma unroll
      for (int k = 0; k < 12; ++k) {
        int q = tid + 256 * k;
        int row = q >> 6, col = (q & 63) * 4;
        float4 v = pf[k];
        h4_t h; h[0] = (half_t)v.x; h[1] = (half_t)v.y; h[2] = (half_t)v.z; h[3] = (half_t)v.w;
        *(h4_t*)(&Bsm[cur ^ 1][row][col]) = h;
      }
    }
#pragma unroll
    for (int nt = 0; nt < 3; ++nt) {
      f32x4 a = (nt == 0) ? acc0 : (nt == 1) ? acc1 : acc2;
      int n = c * 48 + nt * 16 + colc;
      int gsel = n >> 8, jj = n & 255;
      const float* bp = (gsel == 0) ? bu : (gsel == 1) ? br : bn;
      float bias = bp[jj];
#pragma unroll
      for (int rr = 0; rr < 4; ++rr) {
        int m = rbase + rr;  // batch
        half_t hv = (half_t)(a[rr] + bias);
        if (gsel < 2) {
          ((unsigned short*)hs)[(((size_t)m * TT + t) * HH + jj) * 2 + gsel] =
              __builtin_bit_cast(unsigned short, hv);
        } else {
          nbuf[((size_t)m * tcTotal + tl) * HH + jj] = hv;  // [b][t][j] layout
        }
      }
    }
    __syncthreads();
  }
}

// ---------------- Phase B: sequential scan via MFMA + LDS-staged gates ----------------
// Compute structure identical to R8 (passing). New: gates staged in bulk into
// LDS 32 steps ahead via global_load_lds (6 wave-instrs / 32 steps), double-
// buffered. The steady-state step touches ONLY LDS -- no global-load latency
// on the critical path. vmcnt drained once per chunk (on loads issued 32
// steps = ~45k cyc earlier).
// rt uses Wu/xu, zt uses Wr/xr (reference naming quirk); n input is (rt*h)@Wn_h^T.
__global__ __launch_bounds__(512, 2) void gru_rec(
    float* __restrict__ hs,           // u/r gate stash + h output
    const half_t* __restrict__ nbuf,  // n-gate chunk [b][tcTotal][j]
    const float* __restrict__ h0,
    const float* __restrict__ Wu, const float* __restrict__ Wr,
    const float* __restrict__ Wn,
    float* __restrict__ ht, float* __restrict__ hws,
    int t0, int t1, int tcTotal)
{
  __shared__ uint32 urlds[2][CHK * 256];   // 2 x 32 KB (u/r f16-pair per dword)
  __shared__ half_t nlds[2][CHK * 256];    // 2 x 16 KB
  __shared__ __align__(16) half_t h2buf[256];
  __shared__ __align__(16) half_t rh2buf[256];

  const int b = blockIdx.x;
  const int tid = threadIdx.x;
  const int w = tid >> 6;     // wave 0..7
  const int lane = tid & 63;
  const int c16 = lane & 15;
  const int q = lane >> 4;
  const int n0 = 32 * w;
  const int jm = n0 + 16 * (q & 1) + c16;

  h8_t wu[2][8], wr[2][8], wn[2][8];
#pragma unroll
  for (int ct = 0; ct < 2; ++ct) {
    const int j = n0 + ct * 16 + c16;
    const float* pu = Wu + (size_t)j * (EE + HH) + EE + q * 8;
    const float* pr = Wr + (size_t)j * (EE + HH) + EE + q * 8;
    const float* pn = Wn + (size_t)j * (EE + HH) + EE + q * 8;
#pragma unroll
    for (int kt = 0; kt < 8; ++kt) {
      wu[ct][kt] = cvt_w8(pu + kt * 32);
      wr[ct][kt] = cvt_w8(pr + kt * 32);
      wn[ct][kt] = cvt_w8(pn + kt * 32);
    }
  }

  float hm;
  {
    const float* hsrc = (t0 == 0) ? (h0 + (size_t)b * HH) : (hws + (size_t)b * HH);
    hm = hsrc[jm];
    if (tid < 256) h2buf[tid] = (half_t)hsrc[tid];
  }

  const uint32* urg = (const uint32*)hs + ((size_t)b * TT + t0) * HH;  // local step 0
  const half_t* ng = nbuf + (size_t)b * tcTotal * HH;
  float* hout = hs + ((size_t)b * TT + t0) * HH;
  const int nT = t1 - t0;

  // issue one chunk's gate loads (steps [ts, ts+32)) into buffer db
  auto issue_chunk = [&](int ts, int db) {
#pragma unroll
    for (int k = 0; k < 4; ++k) {  // u/r: 32 x 1KB instrs, wave w takes i = 4w+k
      int i = 4 * w + k;
      const char* src = (const char*)(urg + (size_t)(ts + i) * 256) + lane * 16;
      gl2lds16(src, &urlds[db][(size_t)i * 256]);
    }
#pragma unroll
    for (int k = 0; k < 2; ++k) {  // n: 16 x 1KB instrs, wave w takes i = 2w+k
      int i = 2 * w + k;
      const char* src = (const char*)(ng + (size_t)ts * 256 + (size_t)i * 512) + lane * 16;
      gl2lds16(src, &nlds[db][(size_t)i * 512]);
    }
  };

  issue_chunk(0, 0);
  wait_vm0();
  __syncthreads();  // h2buf init + chunk 0 ready

  const f32x4 z4 = {0.f, 0.f, 0.f, 0.f};
  int db = 0;

  for (int tc0 = 0; tc0 < nT; tc0 += CHK) {
    if (tc0 + CHK < nT) issue_chunk(tc0 + CHK, db ^ 1);
    const int cn = (nT - tc0 < CHK) ? (nT - tc0) : CHK;

    for (int s = 0; s < cn; ++s) {
      // gate values for this step (LDS only)
      uint32 urv = urlds[db][s * 256 + jm];
      float xnm = (float)nlds[db][s * 256 + jm];

      // ---- phase 1: u matvec (A = broadcast h); 4 chains of 2 per tile ----
      h8_t ha[8];
#pragma unroll
      for (int kt = 0; kt < 8; ++kt) ha[kt] = *(const h8_t*)(h2buf + kt * 32 + q * 8);
      f32x4 u00 = MFMA16(ha[1], wu[0][1], MFMA16(ha[0], wu[0][0], z4));
      f32x4 u01 = MFMA16(ha[3], wu[0][3], MFMA16(ha[2], wu[0][2], z4));
      f32x4 u02 = MFMA16(ha[5], wu[0][5], MFMA16(ha[4], wu[0][4], z4));
      f32x4 u03 = MFMA16(ha[7], wu[0][7], MFMA16(ha[6], wu[0][6], z4));
      f32x4 u10 = MFMA16(ha[1], wu[1][1], MFMA16(ha[0], wu[1][0], z4));
      f32x4 u11 = MFMA16(ha[3], wu[1][3], MFMA16(ha[2], wu[1][2], z4));
      f32x4 u12 = MFMA16(ha[5], wu[1][5], MFMA16(ha[4], wu[1][4], z4));
      f32x4 u13 = MFMA16(ha[7], wu[1][7], MFMA16(ha[6], wu[1][6], z4));
      float suA = (u00[0] + u01[0]) + (u02[0] + u03[0]);
      float suB = (u10[0] + u11[0]) + (u12[0] + u13[0]);
      float sum = (q & 1) ? suB : suA;
      float xum = (float)__builtin_bit_cast(half_t, (unsigned short)(urv & 0xffffu));
      float rtm = sigmoid_f(xum + sum);
      if (q < 2) rh2buf[jm] = (half_t)(rtm * hm);  // rt * h (pre-matmul!)
      barrier_lgkm();

      // ---- phase 2: r matvec (from ha regs) + n matvec (from rh2buf) ----
      h8_t ra[8];
#pragma unroll
      for (int kt = 0; kt < 8; ++kt) ra[kt] = *(const h8_t*)(rh2buf + kt * 32 + q * 8);
      f32x4 r00 = z4, r01 = z4, r10 = z4, r11 = z4;
#pragma unroll
      for (int kt = 0; kt < 4; ++kt) {
        r00 = MFMA16(ha[kt], wr[0][kt], r00);
        r10 = MFMA16(ha[kt], wr[1][kt], r10);
      }
#pragma unroll
      for (int kt = 4; kt < 8; ++kt) {
        r01 = MFMA16(ha[kt], wr[0][kt], r01);
        r11 = MFMA16(ha[kt], wr[1][kt], r11);
      }
      f32x4 n00 = z4, n01 = z4, n10 = z4, n11 = z4;
#pragma unroll
      for (int kt = 0; kt < 4; ++kt) {
        n00 = MFMA16(ra[kt], wn[0][kt], n00);
        n10 = MFMA16(ra[kt], wn[1][kt], n10);
      }
#pragma unroll
      for (int kt = 4; kt < 8; ++kt) {
        n01 = MFMA16(ra[kt], wn[0][kt], n01);
        n11 = MFMA16(ra[kt], wn[1][kt], n11);
      }
      float srA = r00[0] + r01[0], srB = r10[0] + r11[0];
      float snA = n00[0] + n01[0], snB = n10[0] + n11[0];
      float srm = (q & 1) ? srB : srA;
      float snm = (q & 1) ? snB : snA;
      float xrm = (float)__builtin_bit_cast(half_t, (unsigned short)(urv >> 16));
      float ztm = sigmoid_f(xrm + srm);
      float prem = xnm + snm;
      prem = fminf(fmaxf(prem, -15.f), 15.f);
      float e = __expf(-2.f * prem);
      float nvm = (1.f - e) * FRCP(1.f + e);  // tanh
      float hnm = nvm + ztm * (hm - nvm);     // (1-z)*n + z*h
      hm = hnm;
      if (q < 2) {
        h2buf[jm] = (half_t)hnm;
        hout[(size_t)(tc0 + s) * HH + jm] = hnm;
      }
      barrier_lgkm();
    }

    // chunk boundary: next chunk landed; all waves done with buffer db
    wait_vm0();
    __syncthreads();
    db ^= 1;
  }

  if (q < 2) {
    float* dst = (t1 == TT) ? (ht + (size_t)b * HH) : (hws + (size_t)b * HH);
    dst[jm] = hm;
  }
}

extern "C" void kernel_launch(void* const* d_in, const int* in_sizes, int n_in,
                              void* d_out, int out_size, void* d_ws, size_t ws_size,
                              hipStream_t stream)
{
  (void)in_sizes; (void)n_in; (void)out_size;
  const float* x  = (const float*)d_in[0];
  const float* h0 = (const float*)d_in[1];
  const float* Wu = (const float*)d_in[2];
  const float* bu = (const float*)d_in[3];
  const float* Wr = (const float*)d_in[4];
  const float* br = (const float*)d_in[5];
  const float* Wn = (const float*)d_in[6];
  const float* bn = (const float*)d_in[7];
  float* hs = (float*)d_out;
  float* ht = hs + (size_t)BQ * TT * HH;
  float* hws = (float*)d_ws;                      // 64 KB h carry
  half_t* nbuf = (half_t*)((char*)d_ws + 65536);  // n-gate chunks [b][tc][j]

  const size_t per_step = (size_t)BQ * HH * sizeof(half_t);  // 32 KB/step
  size_t avail = (ws_size > 65536) ? ws_size - 65536 : 0;
  int Tc = (int)(avail / per_step);
  Tc &= ~(CHK - 1);  // multiple of 32 so chunks are always full
  if (Tc > TT) Tc = TT;
  if (Tc < CHK) Tc = CHK;

  for (int t0 = 0; t0 < TT; t0 += Tc) {
    int tc = (TT - t0 < Tc) ? (TT - t0) : Tc;
    gru_xproj<<<dim3(tc), 256, 0, stream>>>(x, Wu, bu, Wr, br, Wn, bn, hs, nbuf, t0);
    gru_rec<<<dim3(BQ), 512, 0, stream>>>(hs, nbuf, h0, Wu, Wr, Wn, ht, hws, t0, t0 + tc, tc);
  }
}